// Round 1
// baseline (424.926 us; speedup 1.0000x reference)
//
#include <hip/hip_runtime.h>
#include <hip/hip_bf16.h>

typedef __attribute__((ext_vector_type(8))) short bf16x8;
typedef __attribute__((ext_vector_type(4))) float f32x4;

#define LDS_XW 0
#define LDS_Q  16384
#define LDS_K  32768
#define LDS_V  49152
// attL (64x64 bf16, pitch 128B) overlays LDS_Q; OL (64x128 bf16, pitch 256B) overlays LDS_K

__device__ __forceinline__ int sw256(int o){ return o ^ (((o >> 8) & 7) << 4); }
__device__ __forceinline__ int sw128(int o){ return o ^ (((o >> 7) & 7) << 4); }

__device__ __forceinline__ short f2bf(float f){
  union { float f; unsigned u; } v; v.f = f;
  unsigned r = v.u + 0x7FFFu + ((v.u >> 16) & 1u);
  return (short)(r >> 16);
}

__global__ void cvt4(const float* __restrict__ a, const float* __restrict__ b,
                     const float* __restrict__ c, const float* __restrict__ d,
                     short* __restrict__ dst) {
  int i = blockIdx.x * 256 + threadIdx.x;          // 0 .. 524287
  int which = i >> 17, off = i & 131071;
  const float* s = (which == 0) ? a : (which == 1) ? b : (which == 2) ? c : d;
  dst[i] = f2bf(s[off]);
}

__global__ __launch_bounds__(256, 2) void swattn_main(
    const float* __restrict__ x, const float* __restrict__ mask,
    const float* __restrict__ Bp,
    const float* __restrict__ wq_b, const float* __restrict__ wk_b,
    const float* __restrict__ wv_b, const float* __restrict__ proj_b,
    const short* __restrict__ wq, const short* __restrict__ wk,
    const short* __restrict__ wv, const short* __restrict__ pw,
    float* __restrict__ out)
{
  __shared__ alignas(16) char smem[65536];
  const int tid  = threadIdx.x;
  const int wvid = tid >> 6, lane = tid & 63, lr = lane & 15, lg = lane >> 4;
  const int wid = blockIdx.x;
  const int bb = wid >> 8, wy = (wid >> 4) & 15, wx = wid & 15;

  // ---- gather shifted window into LDS as bf16 ----
  {
    int token = tid >> 2, q = tid & 3;
    int py = token >> 3, px = token & 7;
    int Y = (wy*8 + py + 4) & 127;
    int X = (wx*8 + px + 4) & 127;
    int swin = bb*256 + ((Y>>3)<<4) + (X>>3);
    int stok = ((Y&7)<<3) + (X&7);
    const float* src = x + ((size_t)(swin*64 + stok))*128 + q*32;
    int base = LDS_XW + token*256 + q*64;
    for (int j = 0; j < 32; j += 8) {
      float4 f0 = *(const float4*)(src + j);
      float4 f1 = *(const float4*)(src + j + 4);
      bf16x8 bv;
      bv[0]=f2bf(f0.x); bv[1]=f2bf(f0.y); bv[2]=f2bf(f0.z); bv[3]=f2bf(f0.w);
      bv[4]=f2bf(f1.x); bv[5]=f2bf(f1.y); bv[6]=f2bf(f1.z); bv[7]=f2bf(f1.w);
      *(bf16x8*)(smem + sw256(base + j*2)) = bv;
    }
  }
  __syncthreads();

  f32x4 accO[4][2];
  for (int rb = 0; rb < 4; ++rb)
    for (int c2 = 0; c2 < 2; ++c2)
      accO[rb][c2] = f32x4{0.f, 0.f, 0.f, 0.f};

  const float isdk = 0.088388347648318447f;  // 1/sqrt(128)
  const float* mrow = nullptr;               // post-softmax multiplicative mask
  if (wy == 15 && wx != 15)      mrow = mask;
  else if (wx == 15 && wy != 15) mrow = mask + 4096;
  else if (wy == 15 && wx == 15) mrow = mask + 8192;

  for (int h = 0; h < 8; ++h) {
    // ======== Phase 1: Q, K, V projections (per-wave 32-col slice) ========
    {
      const short* wmat[3] = { wq, wk, wv };
      const float* bvec[3] = { wq_b, wk_b, wv_b };
      for (int s = 0; s < 3; ++s) {
        bf16x8 bf[2][4];
        for (int c2 = 0; c2 < 2; ++c2) {
          int j = (2*wvid + c2)*16 + lr;
          const short* wr = wmat[s] + (size_t)(h*128 + j)*128;
          for (int kk = 0; kk < 4; ++kk)
            bf[c2][kk] = *(const bf16x8*)(wr + kk*32 + lg*8);
        }
        for (int rb = 0; rb < 4; ++rb) {
          bf16x8 af[4];
          int arow = rb*16 + lr;
          for (int kk = 0; kk < 4; ++kk)
            af[kk] = *(const bf16x8*)(smem + sw256(LDS_XW + arow*256 + kk*64 + lg*16));
          f32x4 a0 = f32x4{0.f,0.f,0.f,0.f}, a1 = f32x4{0.f,0.f,0.f,0.f};
          for (int kk = 0; kk < 4; ++kk) {
            a0 = __builtin_amdgcn_mfma_f32_16x16x32_bf16(af[kk], bf[0][kk], a0, 0,0,0);
            a1 = __builtin_amdgcn_mfma_f32_16x16x32_bf16(af[kk], bf[1][kk], a1, 0,0,0);
          }
          for (int c2 = 0; c2 < 2; ++c2) {
            int j = (2*wvid + c2)*16 + lr;
            float bias = bvec[s][h*128 + j];
            f32x4 acc = c2 ? a1 : a0;
            if (s < 2) {  // Q/K row-major [token][j], pitch 256B
              int ldsb = (s == 0) ? LDS_Q : LDS_K;
              for (int rr = 0; rr < 4; ++rr) {
                int row = rb*16 + lg*4 + rr;
                *(short*)(smem + sw256(ldsb + row*256 + j*2)) = f2bf(acc[rr] + bias);
              }
            } else {      // V transposed: VT[j][m], pitch 128B, pack 4 m's
              short4 p;
              p.x = f2bf(acc[0] + bias); p.y = f2bf(acc[1] + bias);
              p.z = f2bf(acc[2] + bias); p.w = f2bf(acc[3] + bias);
              int m0 = rb*16 + lg*4;
              *(short4*)(smem + sw128(LDS_V + j*128 + m0*2)) = p;
            }
          }
        }
      }
    }
    __syncthreads();

    // ======== Phase 2: att = softmax(QK^T/sdk + Bp) * wmask ========
    float pv[4][4];  // [cb][rr]
    {
      bf16x8 qf[4];
      int qrow = 16*wvid + lr;
      for (int kk = 0; kk < 4; ++kk)
        qf[kk] = *(const bf16x8*)(smem + sw256(LDS_Q + qrow*256 + kk*64 + lg*16));
      int i0 = 16*wvid + lg*4;
      for (int cb = 0; cb < 4; ++cb) {
        f32x4 at = f32x4{0.f,0.f,0.f,0.f};
        int krow = cb*16 + lr;
        for (int kk = 0; kk < 4; ++kk) {
          bf16x8 kf = *(const bf16x8*)(smem + sw256(LDS_K + krow*256 + kk*64 + lg*16));
          at = __builtin_amdgcn_mfma_f32_16x16x32_bf16(qf[kk], kf, at, 0,0,0);
        }
        for (int rr = 0; rr < 4; ++rr)
          pv[cb][rr] = at[rr]*isdk + Bp[(i0+rr)*64 + cb*16 + lr];
      }
      for (int rr = 0; rr < 4; ++rr) {
        float m = fmaxf(fmaxf(pv[0][rr], pv[1][rr]), fmaxf(pv[2][rr], pv[3][rr]));
        m = fmaxf(m, __shfl_xor(m, 1));
        m = fmaxf(m, __shfl_xor(m, 2));
        m = fmaxf(m, __shfl_xor(m, 4));
        m = fmaxf(m, __shfl_xor(m, 8));
        float s = 0.f;
        for (int cb = 0; cb < 4; ++cb) { pv[cb][rr] = __expf(pv[cb][rr] - m); s += pv[cb][rr]; }
        s += __shfl_xor(s, 1); s += __shfl_xor(s, 2);
        s += __shfl_xor(s, 4); s += __shfl_xor(s, 8);
        float inv = 1.0f / s;
        for (int cb = 0; cb < 4; ++cb) pv[cb][rr] *= inv;
      }
      if (mrow) {
        for (int cb = 0; cb < 4; ++cb)
          for (int rr = 0; rr < 4; ++rr)
            pv[cb][rr] *= mrow[(i0+rr)*64 + cb*16 + lr];
      }
    }
    __syncthreads();   // all QL/KL reads done before attL overlay write
    {
      int i0 = 16*wvid + lg*4;
      for (int cb = 0; cb < 4; ++cb) {
        int mcol = cb*16 + lr;
        for (int rr = 0; rr < 4; ++rr)
          *(short*)(smem + sw128(LDS_Q + (i0+rr)*128 + mcol*2)) = f2bf(pv[cb][rr]);
      }
    }
    __syncthreads();

    // ======== Phase 3: O = att @ V (write OL row-major, overlay LDS_K) ========
    {
      bf16x8 vf[2][2];
      for (int c2 = 0; c2 < 2; ++c2) {
        int d = (2*wvid + c2)*16 + lr;
        for (int kk = 0; kk < 2; ++kk)
          vf[c2][kk] = *(const bf16x8*)(smem + sw128(LDS_V + d*128 + kk*64 + lg*16));
      }
      for (int rb = 0; rb < 4; ++rb) {
        bf16x8 paf[2];
        int arow = rb*16 + lr;
        for (int kk = 0; kk < 2; ++kk)
          paf[kk] = *(const bf16x8*)(smem + sw128(LDS_Q + arow*128 + kk*64 + lg*16));
        f32x4 o0 = f32x4{0.f,0.f,0.f,0.f}, o1 = f32x4{0.f,0.f,0.f,0.f};
        for (int kk = 0; kk < 2; ++kk) {
          o0 = __builtin_amdgcn_mfma_f32_16x16x32_bf16(paf[kk], vf[0][kk], o0, 0,0,0);
          o1 = __builtin_amdgcn_mfma_f32_16x16x32_bf16(paf[kk], vf[1][kk], o1, 0,0,0);
        }
        for (int c2 = 0; c2 < 2; ++c2) {
          int d = (2*wvid + c2)*16 + lr;
          f32x4 oo = c2 ? o1 : o0;
          for (int rr = 0; rr < 4; ++rr) {
            int row = rb*16 + lg*4 + rr;
            *(short*)(smem + sw256(LDS_K + row*256 + d*2)) = f2bf(oo[rr]);
          }
        }
      }
    }
    __syncthreads();

    // ======== Phase 4: accO += O @ pw_h^T ========
    {
      bf16x8 pf[2][4];
      for (int c2 = 0; c2 < 2; ++c2) {
        int c = (2*wvid + c2)*16 + lr;
        const short* pr = pw + (size_t)c*1024 + h*128;
        for (int kk = 0; kk < 4; ++kk)
          pf[c2][kk] = *(const bf16x8*)(pr + kk*32 + lg*8);
      }
      for (int rb = 0; rb < 4; ++rb) {
        bf16x8 of[4];
        int arow = rb*16 + lr;
        for (int kk = 0; kk < 4; ++kk)
          of[kk] = *(const bf16x8*)(smem + sw256(LDS_K + arow*256 + kk*64 + lg*16));
        for (int kk = 0; kk < 4; ++kk) {
          accO[rb][0] = __builtin_amdgcn_mfma_f32_16x16x32_bf16(of[kk], pf[0][kk], accO[rb][0], 0,0,0);
          accO[rb][1] = __builtin_amdgcn_mfma_f32_16x16x32_bf16(of[kk], pf[1][kk], accO[rb][1], 0,0,0);
        }
      }
    }
    __syncthreads();   // protect OL before next head's phase-1 overwrites LDS_K
  }

  // ---- epilogue: + proj_b, scatter with reverse shift ----
  for (int rb = 0; rb < 4; ++rb) {
    int ibase = rb*16 + lg*4;
    for (int rr = 0; rr < 4; ++rr) {
      int i = ibase + rr;
      int py = i >> 3, px = i & 7;
      int Y = (wy*8 + py + 4) & 127;
      int X = (wx*8 + px + 4) & 127;
      int dwin = bb*256 + ((Y>>3)<<4) + (X>>3);
      int dtok = ((Y&7)<<3) + (X&7);
      float* dst = out + ((size_t)(dwin*64 + dtok))*128;
      for (int c2 = 0; c2 < 2; ++c2) {
        int c = (2*wvid + c2)*16 + lr;
        dst[c] = accO[rb][c2][rr] + proj_b[c];
      }
    }
  }
}

extern "C" void kernel_launch(void* const* d_in, const int* in_sizes, int n_in,
                              void* d_out, int out_size, void* d_ws, size_t ws_size,
                              hipStream_t stream) {
  (void)in_sizes; (void)n_in; (void)out_size; (void)ws_size;
  const float* x      = (const float*)d_in[0];
  const float* mask   = (const float*)d_in[1];
  const float* Bp     = (const float*)d_in[2];
  const float* wq_w   = (const float*)d_in[3];
  const float* wq_b   = (const float*)d_in[4];
  const float* wk_w   = (const float*)d_in[5];
  const float* wk_b   = (const float*)d_in[6];
  const float* wv_w   = (const float*)d_in[7];
  const float* wv_b   = (const float*)d_in[8];
  const float* proj_w = (const float*)d_in[9];
  const float* proj_b = (const float*)d_in[10];
  float* out = (float*)d_out;
  short* wsb = (short*)d_ws;   // [wq|wk|wv|pw] bf16, 4*131072 shorts = 1 MB

  cvt4<<<2048, 256, 0, stream>>>(wq_w, wk_w, wv_w, proj_w, wsb);
  swattn_main<<<1024, 256, 0, stream>>>(x, mask, Bp, wq_b, wk_b, wv_b, proj_b,
      wsb, wsb + 131072, wsb + 262144, wsb + 393216, out);
}